// Round 1
// baseline (258.018 us; speedup 1.0000x reference)
//
#include <hip/hip_runtime.h>

// Problem constants (from reference):
//   y_pred: [2, 2, 128, 256, 256] f32   y_true: [2, 128, 256, 256] i32
//   NUM_CLASSES=2, THRESHOLD=0.5
// With C=2 the argmax over positive classes is identically 1, so only the
// class-1 channel of y_pred is ever read. Everything reduces to 3 counters.
static constexpr long long PER_BATCH         = 128LL * 256 * 256;      // 8,388,608
static constexpr long long N_TOTAL           = 2 * PER_BATCH;          // 16,777,216
static constexpr long long PRED_BATCH_STRIDE = 2 * PER_BATCH;          // 16,777,216 (c-stride = PER_BATCH)
static constexpr long long NV                = N_TOTAL / 4;            // float4-vectorized count
static constexpr long long NVB               = PER_BATCH / 4;          // 2^21 vec-elems per batch

__global__ void _cm_zero_kernel(unsigned int* __restrict__ c) {
    if (threadIdx.x < 3) c[threadIdx.x] = 0u;
}

__global__ __launch_bounds__(256) void _cm_count_kernel(
        const float* __restrict__ y_pred,
        const int*   __restrict__ y_true,
        unsigned int* __restrict__ counters) {
    long long tid    = (long long)blockIdx.x * blockDim.x + threadIdx.x;
    long long stride = (long long)gridDim.x * blockDim.x;

    unsigned int ct = 0, cp = 0, cb = 0;
    const int4* tvec = reinterpret_cast<const int4*>(y_true);

    for (long long v = tid; v < NV; v += stride) {
        long long b = v >> 21;            // NVB == 2^21
        long long r = v & (NVB - 1);
        const float4* pvec =
            reinterpret_cast<const float4*>(y_pred + b * PRED_BATCH_STRIDE + PER_BATCH);
        float4 pv = pvec[r];
        int4   tv = tvec[v];

        unsigned int t0 = (tv.x == 1), t1 = (tv.y == 1), t2 = (tv.z == 1), t3 = (tv.w == 1);
        unsigned int p0 = (pv.x > 0.5f), p1 = (pv.y > 0.5f), p2 = (pv.z > 0.5f), p3 = (pv.w > 0.5f);
        ct += t0 + t1 + t2 + t3;
        cp += p0 + p1 + p2 + p3;
        cb += (t0 & p0) + (t1 & p1) + (t2 & p2) + (t3 & p3);
    }

    // wave64 shuffle reduction
    #pragma unroll
    for (int off = 32; off > 0; off >>= 1) {
        ct += __shfl_down(ct, off);
        cp += __shfl_down(cp, off);
        cb += __shfl_down(cb, off);
    }

    __shared__ unsigned int s[3];
    if (threadIdx.x == 0) { s[0] = 0u; s[1] = 0u; s[2] = 0u; }
    __syncthreads();
    if ((threadIdx.x & 63) == 0) {
        atomicAdd(&s[0], ct);
        atomicAdd(&s[1], cp);
        atomicAdd(&s[2], cb);
    }
    __syncthreads();
    if (threadIdx.x == 0) {
        atomicAdd(&counters[0], s[0]);
        atomicAdd(&counters[1], s[1]);
        atomicAdd(&counters[2], s[2]);
    }
}

__global__ void _cm_finalize_kernel(const unsigned int* __restrict__ counters,
                                    int* __restrict__ out) {
    if (threadIdx.x == 0) {
        int ct = (int)counters[0];
        int cp = (int)counters[1];
        int cb = (int)counters[2];
        int cm11 = cb;
        int cm10 = ct - cb;
        int cm01 = cp - cb;
        int cm00 = (int)N_TOTAL - ct - cp + cb;
        // outputs flat in return order: cm (row-major 2x2), tps[1], fps[1], fns[1], tns[1]
        out[0] = cm00; out[1] = cm01;
        out[2] = cm10; out[3] = cm11;
        out[4] = cm11;   // tps[1]
        out[5] = cm01;   // fps[1]
        out[6] = cm10;   // fns[1]
        out[7] = cm00;   // tns[1]
    }
}

extern "C" void kernel_launch(void* const* d_in, const int* in_sizes, int n_in,
                              void* d_out, int out_size, void* d_ws, size_t ws_size,
                              hipStream_t stream) {
    const float* y_pred = (const float*)d_in[0];
    const int*   y_true = (const int*)d_in[1];
    unsigned int* counters = (unsigned int*)d_ws;   // 3 x u32, poisoned 0xAA each call
    int* out = (int*)d_out;

    _cm_zero_kernel<<<1, 64, 0, stream>>>(counters);

    // memory-bound: cap grid, grid-stride the rest (G11). 2048 blocks x 256 thr
    // = 524,288 threads, 8 float4-iters each over NV = 4,194,304.
    _cm_count_kernel<<<2048, 256, 0, stream>>>(y_pred, y_true, counters);

    _cm_finalize_kernel<<<1, 64, 0, stream>>>(counters, out);
}

// Round 2
// 213.841 us; speedup vs baseline: 1.2066x; 1.2066x over previous
//
#include <hip/hip_runtime.h>

// y_pred: [2, 2, 128, 256, 256] f32   y_true: [2, 128, 256, 256] i32
// C=2 -> argmax over positive classes == 1 always; only channel 1 of y_pred
// is read. Whole op reduces to 3 counters: ct=#(yt==1), cp=#(p1>0.5),
// cb=#(both). cm/tps/fps/fns/tns are closed forms of {ct,cp,cb,N}.
static constexpr long long PER_BATCH = 128LL * 256 * 256;   // 8,388,608
static constexpr long long N_TOTAL   = 2 * PER_BATCH;       // 16,777,216
static constexpr long long NV        = N_TOTAL / 4;         // 4,194,304 vec4 elems
static constexpr long long NVB       = PER_BATCH / 4;       // 2,097,152

static constexpr int       BLOCKS = 2048;
static constexpr int       TPB    = 256;
static constexpr long long T      = (long long)BLOCKS * TPB; // 524,288 threads
// NV / T == 8 iterations/thread; 4*T == NVB, so batch split is at i==4 and
// both batches index with tid + i*T, i in [0,4).

__global__ __launch_bounds__(256) void _cm_count_kernel(
        const float* __restrict__ y_pred,
        const int*   __restrict__ y_true,
        unsigned int* __restrict__ partials) {   // [3][BLOCKS] in d_ws
    const long long tid = (long long)blockIdx.x * TPB + threadIdx.x;

    const float4* __restrict__ p0 = reinterpret_cast<const float4*>(y_pred + PER_BATCH);      // b0, ch1
    const float4* __restrict__ p1 = reinterpret_cast<const float4*>(y_pred + 3 * PER_BATCH);  // b1, ch1
    const int4*   __restrict__ tv = reinterpret_cast<const int4*>(y_true);

    // Issue all 16 loads with compile-time strides -> max memory-level ILP.
    int4   t[8];
    float4 p[8];
    #pragma unroll
    for (int i = 0; i < 8; ++i) t[i] = tv[tid + i * T];
    #pragma unroll
    for (int i = 0; i < 4; ++i) p[i] = p0[tid + i * T];
    #pragma unroll
    for (int i = 0; i < 4; ++i) p[i + 4] = p1[tid + i * T];   // (tid+(i+4)*T) - NVB == tid+i*T

    unsigned int ct = 0, cp = 0, cb = 0;
    #pragma unroll
    for (int i = 0; i < 8; ++i) {
        unsigned int t0 = (t[i].x == 1), t1 = (t[i].y == 1), t2 = (t[i].z == 1), t3 = (t[i].w == 1);
        unsigned int q0 = (p[i].x > 0.5f), q1 = (p[i].y > 0.5f), q2 = (p[i].z > 0.5f), q3 = (p[i].w > 0.5f);
        ct += t0 + t1 + t2 + t3;
        cp += q0 + q1 + q2 + q3;
        cb += (t0 & q0) + (t1 & q1) + (t2 & q2) + (t3 & q3);
    }

    // wave64 shuffle reduction
    #pragma unroll
    for (int off = 32; off > 0; off >>= 1) {
        ct += __shfl_down(ct, off);
        cp += __shfl_down(cp, off);
        cb += __shfl_down(cb, off);
    }

    __shared__ unsigned int s[3][4];            // 4 waves/block
    const int wave = threadIdx.x >> 6;
    if ((threadIdx.x & 63) == 0) { s[0][wave] = ct; s[1][wave] = cp; s[2][wave] = cb; }
    __syncthreads();
    if (threadIdx.x == 0) {
        partials[              blockIdx.x] = s[0][0] + s[0][1] + s[0][2] + s[0][3];
        partials[    BLOCKS + blockIdx.x] = s[1][0] + s[1][1] + s[1][2] + s[1][3];
        partials[2 * BLOCKS + blockIdx.x] = s[2][0] + s[2][1] + s[2][2] + s[2][3];
    }
}

__global__ __launch_bounds__(256) void _cm_finalize_kernel(
        const unsigned int* __restrict__ partials,
        int* __restrict__ out) {
    // 256 threads; each sums 8 entries of each of the 3 partial arrays.
    unsigned int ct = 0, cp = 0, cb = 0;
    #pragma unroll
    for (int i = 0; i < BLOCKS / TPB; ++i) {
        ct += partials[              threadIdx.x + i * TPB];
        cp += partials[    BLOCKS + threadIdx.x + i * TPB];
        cb += partials[2 * BLOCKS + threadIdx.x + i * TPB];
    }
    #pragma unroll
    for (int off = 32; off > 0; off >>= 1) {
        ct += __shfl_down(ct, off);
        cp += __shfl_down(cp, off);
        cb += __shfl_down(cb, off);
    }
    __shared__ unsigned int s[3][4];
    const int wave = threadIdx.x >> 6;
    if ((threadIdx.x & 63) == 0) { s[0][wave] = ct; s[1][wave] = cp; s[2][wave] = cb; }
    __syncthreads();
    if (threadIdx.x == 0) {
        int fct = (int)(s[0][0] + s[0][1] + s[0][2] + s[0][3]);
        int fcp = (int)(s[1][0] + s[1][1] + s[1][2] + s[1][3]);
        int fcb = (int)(s[2][0] + s[2][1] + s[2][2] + s[2][3]);
        int cm11 = fcb;
        int cm10 = fct - fcb;
        int cm01 = fcp - fcb;
        int cm00 = (int)N_TOTAL - fct - fcp + fcb;
        out[0] = cm00; out[1] = cm01;
        out[2] = cm10; out[3] = cm11;
        out[4] = cm11;   // tps[1]
        out[5] = cm01;   // fps[1]
        out[6] = cm10;   // fns[1]
        out[7] = cm00;   // tns[1]
    }
}

extern "C" void kernel_launch(void* const* d_in, const int* in_sizes, int n_in,
                              void* d_out, int out_size, void* d_ws, size_t ws_size,
                              hipStream_t stream) {
    const float* y_pred = (const float*)d_in[0];
    const int*   y_true = (const int*)d_in[1];
    unsigned int* partials = (unsigned int*)d_ws;   // 3*BLOCKS u32 = 24 KB, fully overwritten
    int* out = (int*)d_out;

    _cm_count_kernel<<<BLOCKS, TPB, 0, stream>>>(y_pred, y_true, partials);
    _cm_finalize_kernel<<<1, TPB, 0, stream>>>(partials, out);
}